// Round 2
// baseline (4033.772 us; speedup 1.0000x reference)
//
#include <hip/hip_runtime.h>
#include <math.h>

#define DEV __device__ __forceinline__

constexpr int DDm = 32, HHm = 64, WWm = 64;
constexpr int NN = DDm * HHm * WWm;  // 131072

DEV float gelu_f(float x) {
  return 0.5f * x * (1.0f + erff(x * 0.7071067811865475f));
}

// ---------------- conv1x1: y[o][n] = sum_c w[o][c] * x[c][n] ----------------
template<int CIN, int COUT>
__global__ __launch_bounds__(256)
void conv1x1_kernel(const float* __restrict__ x, const float* __restrict__ w,
                    float* __restrict__ y) {
  const int n = blockIdx.x * 256 + threadIdx.x;
  float acc[COUT];
#pragma unroll
  for (int o = 0; o < COUT; ++o) acc[o] = 0.f;
  for (int c = 0; c < CIN; ++c) {
    const float xc = x[(size_t)c * NN + n];
#pragma unroll
    for (int o = 0; o < COUT; ++o) acc[o] = fmaf(w[o * CIN + c], xc, acc[o]);
  }
#pragma unroll
  for (int o = 0; o < COUT; ++o) y[(size_t)o * NN + n] = acc[o];
}

// ------------- depthwise 3x3x3 (pad 1) + exact GELU; grid=(N/256, C) --------
__global__ __launch_bounds__(256)
void dw3_gelu_kernel(const float* __restrict__ v, const float* __restrict__ w,
                     float* __restrict__ z) {
  const int n = blockIdx.x * 256 + threadIdx.x;
  const int c = blockIdx.y;
  const int wp = n % WWm;
  const int hp = (n / WWm) % HHm;
  const int dp = n / (WWm * HHm);
  const float* __restrict__ vc = v + (size_t)c * NN;
  const float* __restrict__ wc = w + c * 27;
  float s = 0.f;
#pragma unroll
  for (int t = 0; t < 27; ++t) {
    const int kd = t / 9 - 1, kh = (t / 3) % 3 - 1, kw = t % 3 - 1;
    const int d2 = dp + kd, h2 = hp + kh, w2 = wp + kw;
    if ((unsigned)d2 < (unsigned)DDm && (unsigned)h2 < (unsigned)HHm &&
        (unsigned)w2 < (unsigned)WWm) {
      s = fmaf(wc[t], vc[(d2 * HHm + h2) * WWm + w2], s);
    }
  }
  z[(size_t)c * NN + n] = gelu_f(s);
}

// ---- fused offset/mask projection + softmax + trilinear sampling -----------
// one thread = one (group, voxel). 108 dot products in registers, then
// 27 sampling points; per-thread channel accumulators live in LDS so the
// channel loop can stay a runtime loop (no scratch, small icache).
template<int C, int G, int CG>
__global__ __launch_bounds__(256)
void dcn_fused_kernel(const float* __restrict__ v, const float* __restrict__ z,
                      const float* __restrict__ woff, const float* __restrict__ boff,
                      const float* __restrict__ wmask, const float* __restrict__ bmask,
                      float* __restrict__ out, float sd) {
  const int tid = threadIdx.x;
  const int n = blockIdx.x * 256 + tid;
  const int g = blockIdx.y;

  __shared__ float acc_s[CG * 256];

  // ---- phase 1: 81 offset rows + 27 mask rows, dot over C channels ----
  float oacc[81];
  float macc[27];
#pragma unroll
  for (int r = 0; r < 81; ++r) oacc[r] = boff[g * 81 + r];
#pragma unroll
  for (int k = 0; k < 27; ++k) macc[k] = bmask[g * 27 + k];

  const float* __restrict__ wo = woff + (size_t)g * 81 * C;
  const float* __restrict__ wm = wmask + (size_t)g * 27 * C;
  for (int c = 0; c < C; ++c) {
    const float zc = z[(size_t)c * NN + n];
#pragma unroll
    for (int r = 0; r < 81; ++r) oacc[r] = fmaf(wo[r * C + c], zc, oacc[r]);
#pragma unroll
    for (int k = 0; k < 27; ++k) macc[k] = fmaf(wm[k * C + c], zc, macc[k]);
  }

  // ---- softmax over the 27 mask logits ----
  float mx = macc[0];
#pragma unroll
  for (int k = 1; k < 27; ++k) mx = fmaxf(mx, macc[k]);
  float ssum = 0.f;
#pragma unroll
  for (int k = 0; k < 27; ++k) { macc[k] = expf(macc[k] - mx); ssum += macc[k]; }
  const float rs = 1.f / ssum;
#pragma unroll
  for (int k = 0; k < 27; ++k) macc[k] *= rs;

  // ---- phase 2: sampling ----
  const int wp = n % WWm;
  const int hp = (n / WWm) % HHm;
  const int dp = n / (WWm * HHm);

#pragma unroll
  for (int c = 0; c < CG; ++c) acc_s[c * 256 + tid] = 0.f;

  const float* __restrict__ vg = v + (size_t)g * CG * NN;

#pragma unroll
  for (int k = 0; k < 27; ++k) {
    const int kd = k / 9 - 1, kh = (k / 3) % 3 - 1, kw = k % 3 - 1;
    const float pd = (float)(dp + kd) + oacc[3 * k + 0] * sd;
    const float ph = (float)(hp + kh) + oacc[3 * k + 1];
    const float pw = (float)(wp + kw) + oacc[3 * k + 2];
    const float fd0 = floorf(pd), fh0 = floorf(ph), fw0 = floorf(pw);
    const float fz = pd - fd0, fy = ph - fh0, fx = pw - fw0;
    const int z0 = (int)fd0, y0 = (int)fh0, x0 = (int)fw0;
    const float mk = macc[k];

    float wgt[8];
    int idx[8];
#pragma unroll
    for (int j = 0; j < 8; ++j) {
      const int dz = (j >> 2) & 1, dy = (j >> 1) & 1, dx = j & 1;
      const int iz = z0 + dz, iy = y0 + dy, ix = x0 + dx;
      const bool ok = ((unsigned)iz < (unsigned)DDm) &&
                      ((unsigned)iy < (unsigned)HHm) &&
                      ((unsigned)ix < (unsigned)WWm);
      const float wz = dz ? fz : 1.f - fz;
      const float wy = dy ? fy : 1.f - fy;
      const float wx = dx ? fx : 1.f - fx;
      const int cz = min(max(iz, 0), DDm - 1);
      const int cy = min(max(iy, 0), HHm - 1);
      const int cx = min(max(ix, 0), WWm - 1);
      idx[j] = (cz * HHm + cy) * WWm + cx;
      wgt[j] = ok ? mk * wz * wy * wx : 0.f;
    }

#pragma unroll 2
    for (int c = 0; c < CG; ++c) {
      float a = acc_s[c * 256 + tid];
      const float* __restrict__ vc = vg + (size_t)c * NN;
#pragma unroll
      for (int j = 0; j < 8; ++j) a = fmaf(wgt[j], vc[idx[j]], a);
      acc_s[c * 256 + tid] = a;
    }
  }

  // ---- epilogue ----
  for (int c = 0; c < CG; ++c)
    out[((size_t)(g * CG + c)) * NN + n] = acc_s[c * 256 + tid];
}

// --------- per-channel mean / rstd over N (instance norm stats) -------------
__global__ __launch_bounds__(256)
void stats_kernel(const float* __restrict__ y, float* __restrict__ mean,
                  float* __restrict__ rstd) {
  const int c = blockIdx.x;
  const float* __restrict__ yc = y + (size_t)c * NN;
  float s = 0.f, ss = 0.f;
  for (int i = threadIdx.x; i < NN; i += 256) {
    const float v = yc[i];
    s += v;
    ss = fmaf(v, v, ss);
  }
  __shared__ float sh1[256], sh2[256];
  sh1[threadIdx.x] = s;
  sh2[threadIdx.x] = ss;
  __syncthreads();
  for (int o = 128; o > 0; o >>= 1) {
    if (threadIdx.x < o) {
      sh1[threadIdx.x] += sh1[threadIdx.x + o];
      sh2[threadIdx.x] += sh2[threadIdx.x + o];
    }
    __syncthreads();
  }
  if (threadIdx.x == 0) {
    const float mu = sh1[0] / (float)NN;
    const float var = sh2[0] / (float)NN - mu * mu;
    mean[c] = mu;
    rstd[c] = rsqrtf(var + 1e-5f);
  }
}

// --------- normalize + exact GELU (elementwise over [64][N]) ----------------
__global__ __launch_bounds__(256)
void normgelu_kernel(const float* __restrict__ y, const float* __restrict__ mean,
                     const float* __restrict__ rstd, float* __restrict__ out) {
  const int i = blockIdx.x * 256 + threadIdx.x;
  const int c = i >> 17;  // NN = 2^17
  out[i] = gelu_f((y[i] - mean[c]) * rstd[c]);
}

// --------- post conv1x1 + gated residual: out = c + sg * (Wpost r) ----------
__global__ __launch_bounds__(256)
void post_residual_kernel(const float* __restrict__ r, const float* __restrict__ wpost,
                          const float* __restrict__ cbuf, const float* __restrict__ gate,
                          float* __restrict__ out) {
  const int n = blockIdx.x * 256 + threadIdx.x;
  const float sg = 1.f / (1.f + expf(-gate[0]));
  float acc[64];
#pragma unroll
  for (int o = 0; o < 64; ++o) acc[o] = 0.f;
  for (int c = 0; c < 64; ++c) {
    const float rc = r[(size_t)c * NN + n];
#pragma unroll
    for (int o = 0; o < 64; ++o) acc[o] = fmaf(wpost[o * 64 + c], rc, acc[o]);
  }
#pragma unroll
  for (int o = 0; o < 64; ++o)
    out[(size_t)o * NN + n] = cbuf[(size_t)o * NN + n] + sg * acc[o];
}

// --------- 2x2x2 max pool, stride 2 -----------------------------------------
__global__ __launch_bounds__(256)
void maxpool_kernel(const float* __restrict__ x, float* __restrict__ y) {
  const int i = blockIdx.x * 256 + threadIdx.x;  // 64*16*32*32
  const int ow = i & 31;
  const int oh = (i >> 5) & 31;
  const int od = (i >> 10) & 15;
  const int c = i >> 14;
  const float* __restrict__ xc =
      x + (size_t)c * NN + ((size_t)(od * 2) * HHm + oh * 2) * WWm + ow * 2;
  float m = -INFINITY;
#pragma unroll
  for (int dz = 0; dz < 2; ++dz)
#pragma unroll
    for (int dy = 0; dy < 2; ++dy)
#pragma unroll
      for (int dx = 0; dx < 2; ++dx)
        m = fmaxf(m, xc[(dz * HHm + dy) * WWm + dx]);
  y[i] = m;
}

extern "C" void kernel_launch(void* const* d_in, const int* in_sizes, int n_in,
                              void* d_out, int out_size, void* d_ws, size_t ws_size,
                              hipStream_t stream) {
  const float* x       = (const float*)d_in[0];
  const float* d1_win  = (const float*)d_in[1];
  const float* d1_wdw  = (const float*)d_in[2];
  const float* d1_woff = (const float*)d_in[3];
  const float* d1_boff = (const float*)d_in[4];
  const float* d1_wmask= (const float*)d_in[5];
  const float* d1_bmask= (const float*)d_in[6];
  const float* d1_wout = (const float*)d_in[7];
  const float* d2_win  = (const float*)d_in[8];
  const float* d2_wdw  = (const float*)d_in[9];
  const float* d2_woff = (const float*)d_in[10];
  const float* d2_boff = (const float*)d_in[11];
  const float* d2_wmask= (const float*)d_in[12];
  const float* d2_bmask= (const float*)d_in[13];
  const float* d2_wout = (const float*)d_in[14];
  const float* pre_w   = (const float*)d_in[15];
  const float* d3_win  = (const float*)d_in[16];
  const float* d3_wdw  = (const float*)d_in[17];
  const float* d3_woff = (const float*)d_in[18];
  const float* d3_boff = (const float*)d_in[19];
  const float* d3_wmask= (const float*)d_in[20];
  const float* d3_bmask= (const float*)d_in[21];
  const float* d3_wout = (const float*)d_in[22];
  const float* post_w  = (const float*)d_in[23];
  const float* gate    = (const float*)d_in[24];

  float* out = (float*)d_out;

  // workspace layout: 5 x [64*NN] fp32 buffers + stats
  float* Wv = (float*)d_ws;          // value proj / pre-norm y (aliased)
  float* Wz = Wv + (size_t)64 * NN;  // dwconv+gelu branch
  float* Wa = Wz + (size_t)64 * NN;  // DCN sampling accumulator
  float* Wc = Wa + (size_t)64 * NN;  // residual trunk 'c'
  float* Wr = Wc + (size_t)64 * NN;  // refine branch 'r'
  float* Wm = Wr + (size_t)64 * NN;  // mean[64]
  float* Ws = Wm + 64;               // rstd[64]

  const dim3 blk(256);
  const int nb = NN / 256;  // 512

  // ---- stage d1: 32ch -> 64ch, G=4, Cg=8 ----
  conv1x1_kernel<32, 32><<<nb, blk, 0, stream>>>(x, d1_win, Wv);
  dw3_gelu_kernel<<<dim3(nb, 32), blk, 0, stream>>>(Wv, d1_wdw, Wz);
  dcn_fused_kernel<32, 4, 8><<<dim3(nb, 4), blk, 0, stream>>>(
      Wv, Wz, d1_woff, d1_boff, d1_wmask, d1_bmask, Wa, 1.f);
  conv1x1_kernel<32, 64><<<nb, blk, 0, stream>>>(Wa, d1_wout, Wv);
  stats_kernel<<<64, blk, 0, stream>>>(Wv, Wm, Ws);
  normgelu_kernel<<<64 * nb, blk, 0, stream>>>(Wv, Wm, Ws, Wc);

  // ---- stage d2: 64ch -> 64ch, G=4, Cg=16 ----
  conv1x1_kernel<64, 64><<<nb, blk, 0, stream>>>(Wc, d2_win, Wv);
  dw3_gelu_kernel<<<dim3(nb, 64), blk, 0, stream>>>(Wv, d2_wdw, Wz);
  dcn_fused_kernel<64, 4, 16><<<dim3(nb, 4), blk, 0, stream>>>(
      Wv, Wz, d2_woff, d2_boff, d2_wmask, d2_bmask, Wa, 1.f);
  conv1x1_kernel<64, 64><<<nb, blk, 0, stream>>>(Wa, d2_wout, Wv);
  stats_kernel<<<64, blk, 0, stream>>>(Wv, Wm, Ws);
  normgelu_kernel<<<64 * nb, blk, 0, stream>>>(Wv, Wm, Ws, Wc);

  // ---- pre conv ----
  conv1x1_kernel<64, 64><<<nb, blk, 0, stream>>>(Wc, pre_w, Wr);

  // ---- stage d3: 64ch -> 64ch, G=2, Cg=32, axis_scale=(0.5,1,1) ----
  conv1x1_kernel<64, 64><<<nb, blk, 0, stream>>>(Wr, d3_win, Wv);
  dw3_gelu_kernel<<<dim3(nb, 64), blk, 0, stream>>>(Wv, d3_wdw, Wz);
  dcn_fused_kernel<64, 2, 32><<<dim3(nb, 2), blk, 0, stream>>>(
      Wv, Wz, d3_woff, d3_boff, d3_wmask, d3_bmask, Wa, 0.5f);
  conv1x1_kernel<64, 64><<<nb, blk, 0, stream>>>(Wa, d3_wout, Wv);
  stats_kernel<<<64, blk, 0, stream>>>(Wv, Wm, Ws);
  normgelu_kernel<<<64 * nb, blk, 0, stream>>>(Wv, Wm, Ws, Wr);

  // ---- post conv + gated residual into conv_out ----
  post_residual_kernel<<<nb, blk, 0, stream>>>(Wr, post_w, Wc, gate, out);

  // ---- maxpool into second output ----
  maxpool_kernel<<<(64 * 16 * 32 * 32) / 256, blk, 0, stream>>>(
      out, out + (size_t)64 * NN);
}

// Round 3
// 3179.032 us; speedup vs baseline: 1.2689x; 1.2689x over previous
//
#include <hip/hip_runtime.h>
#include <math.h>

#define DEV __device__ __forceinline__

constexpr int DDm = 32, HHm = 64, WWm = 64;
constexpr int NN = DDm * HHm * WWm;  // 131072

DEV float gelu_f(float x) {
  return 0.5f * x * (1.0f + erff(x * 0.7071067811865475f));
}

// ---------------- conv1x1: y[o][n] = sum_c w[o][c] * x[c][n] ----------------
template<int CIN, int COUT>
__global__ __launch_bounds__(256)
void conv1x1_kernel(const float* __restrict__ x, const float* __restrict__ w,
                    float* __restrict__ y) {
  const int n = blockIdx.x * 256 + threadIdx.x;
  float acc[COUT];
#pragma unroll
  for (int o = 0; o < COUT; ++o) acc[o] = 0.f;
  for (int c = 0; c < CIN; ++c) {
    const float xc = x[(size_t)c * NN + n];
#pragma unroll
    for (int o = 0; o < COUT; ++o) acc[o] = fmaf(w[o * CIN + c], xc, acc[o]);
  }
#pragma unroll
  for (int o = 0; o < COUT; ++o) y[(size_t)o * NN + n] = acc[o];
}

// ------------- depthwise 3x3x3 (pad 1) + exact GELU; grid=(N/256, C) --------
__global__ __launch_bounds__(256)
void dw3_gelu_kernel(const float* __restrict__ v, const float* __restrict__ w,
                     float* __restrict__ z) {
  const int n = blockIdx.x * 256 + threadIdx.x;
  const int c = blockIdx.y;
  const int wp = n % WWm;
  const int hp = (n / WWm) % HHm;
  const int dp = n / (WWm * HHm);
  const float* __restrict__ vc = v + (size_t)c * NN;
  const float* __restrict__ wc = w + c * 27;
  float s = 0.f;
#pragma unroll
  for (int t = 0; t < 27; ++t) {
    const int kd = t / 9 - 1, kh = (t / 3) % 3 - 1, kw = t % 3 - 1;
    const int d2 = dp + kd, h2 = hp + kh, w2 = wp + kw;
    if ((unsigned)d2 < (unsigned)DDm && (unsigned)h2 < (unsigned)HHm &&
        (unsigned)w2 < (unsigned)WWm) {
      s = fmaf(wc[t], vc[(d2 * HHm + h2) * WWm + w2], s);
    }
  }
  z[(size_t)c * NN + n] = gelu_f(s);
}

// ---- fused offset/mask projection + softmax + trilinear sampling -----------
// Register-pressure-aware layout: only the 27 mask accumulators are held
// across the kernel; the 3 offset dot-products are recomputed per k-point
// inside the fully-unrolled k loop (same total FLOPs, z re-read from L1/L2).
// Per (k,c): 4x 8-byte corner-pair loads + 8 FMA; acc[CG] lives in LDS
// (stride-1 per thread, conflict-free) so the channel loop stays runtime.
template<int C, int G, int CG>
__global__ __launch_bounds__(256)
void dcn_fused_kernel(const float* __restrict__ v, const float* __restrict__ z,
                      const float* __restrict__ woff, const float* __restrict__ boff,
                      const float* __restrict__ wmask, const float* __restrict__ bmask,
                      float* __restrict__ out, float sd) {
  const int tid = threadIdx.x;
  const int n = blockIdx.x * 256 + tid;
  const int g = blockIdx.y;

  __shared__ float acc_s[CG * 256];

  // ---- mask logits: 27 dot products over C channels ----
  float macc[27];
#pragma unroll
  for (int k = 0; k < 27; ++k) macc[k] = bmask[g * 27 + k];
  const float* __restrict__ wm = wmask + (size_t)g * 27 * C;
  for (int c = 0; c < C; ++c) {
    const float zc = z[(size_t)c * NN + n];
#pragma unroll
    for (int k = 0; k < 27; ++k) macc[k] = fmaf(wm[k * C + c], zc, macc[k]);
  }

  // ---- softmax over the 27 mask logits ----
  float mx = macc[0];
#pragma unroll
  for (int k = 1; k < 27; ++k) mx = fmaxf(mx, macc[k]);
  float ssum = 0.f;
#pragma unroll
  for (int k = 0; k < 27; ++k) { macc[k] = expf(macc[k] - mx); ssum += macc[k]; }
  const float rs = 1.f / ssum;
#pragma unroll
  for (int k = 0; k < 27; ++k) macc[k] *= rs;

  // ---- init per-thread channel accumulators (LDS, stride-1) ----
#pragma unroll
  for (int c = 0; c < CG; ++c) acc_s[c * 256 + tid] = 0.f;

  const int wp = n & 63;
  const int hp = (n >> 6) & 63;
  const int dp = n >> 12;

  const float* __restrict__ vg = v + (size_t)g * CG * NN;
  const float* __restrict__ wo = woff + (size_t)g * 81 * C;
  const float* __restrict__ bo = boff + g * 81;

#pragma unroll
  for (int k = 0; k < 27; ++k) {
    const int kd = k / 9 - 1, kh = (k / 3) % 3 - 1, kw = k % 3 - 1;

    // ---- offsets for this k: 3 dot products over C (z from L1/L2) ----
    float o0 = bo[3 * k + 0], o1 = bo[3 * k + 1], o2 = bo[3 * k + 2];
    {
      const float* __restrict__ w0 = wo + (size_t)(3 * k + 0) * C;
      const float* __restrict__ w1 = wo + (size_t)(3 * k + 1) * C;
      const float* __restrict__ w2 = wo + (size_t)(3 * k + 2) * C;
      for (int c = 0; c < C; ++c) {
        const float zc = z[(size_t)c * NN + n];
        o0 = fmaf(w0[c], zc, o0);
        o1 = fmaf(w1[c], zc, o1);
        o2 = fmaf(w2[c], zc, o2);
      }
    }

    const float pd = (float)(dp + kd) + o0 * sd;
    const float ph = (float)(hp + kh) + o1;
    const float pw = (float)(wp + kw) + o2;

    // ---- x axis: adjacent corner pair -> one base index + two weights ----
    const float fw0 = floorf(pw);
    const float fx = pw - fw0;
    const int x0 = (int)fw0;
    const int cx = min(max(x0, 0), WWm - 2);
    const float wx0 = 1.f - fx, wx1 = fx;
    // contribution mapping verified against reference valid/clamp semantics:
    //  x0 in [0,62]: (v[x0]*wx0, v[x0+1]*wx1); x0==63: (0, v[63]*wx0);
    //  x0==-1: (v[0]*wx1, 0); else (0,0)
    const float wA = (x0 == cx) ? wx0 : ((x0 == -1) ? wx1 : 0.f);
    const float wB = (x0 == cx) ? wx1 : ((x0 == WWm - 1) ? wx0 : 0.f);

    // ---- z (depth) and y axes: standard per-corner valid+clamp ----
    const float fd0 = floorf(pd);
    const float fz = pd - fd0;
    const int z0 = (int)fd0, z1 = z0 + 1;
    const float vz0 = ((unsigned)z0 < (unsigned)DDm) ? (1.f - fz) : 0.f;
    const float vz1 = ((unsigned)z1 < (unsigned)DDm) ? fz : 0.f;
    const int cz0 = min(max(z0, 0), DDm - 1);
    const int cz1 = min(max(z1, 0), DDm - 1);

    const float fh0 = floorf(ph);
    const float fy = ph - fh0;
    const int y0 = (int)fh0, y1 = y0 + 1;
    const float vy0 = ((unsigned)y0 < (unsigned)HHm) ? (1.f - fy) : 0.f;
    const float vy1 = ((unsigned)y1 < (unsigned)HHm) ? fy : 0.f;
    const int cy0 = min(max(y0, 0), HHm - 1);
    const int cy1 = min(max(y1, 0), HHm - 1);

    const float mk = macc[k];
    const float r0 = mk * vz0 * vy0;  // (z0,y0)
    const float r1 = mk * vz0 * vy1;  // (z0,y1)
    const float r2 = mk * vz1 * vy0;  // (z1,y0)
    const float r3 = mk * vz1 * vy1;  // (z1,y1)

    const int i0 = (cz0 * HHm + cy0) * WWm + cx;
    const int i1 = (cz0 * HHm + cy1) * WWm + cx;
    const int i2 = (cz1 * HHm + cy0) * WWm + cx;
    const int i3 = (cz1 * HHm + cy1) * WWm + cx;

    const float w0A = r0 * wA, w0B = r0 * wB;
    const float w1A = r1 * wA, w1B = r1 * wB;
    const float w2A = r2 * wA, w2B = r2 * wB;
    const float w3A = r3 * wA, w3B = r3 * wB;

#pragma unroll 2
    for (int c = 0; c < CG; ++c) {
      const float* __restrict__ vc = vg + (size_t)c * NN;
      float a = acc_s[c * 256 + tid];
      float2 q0, q1, q2, q3;
      __builtin_memcpy(&q0, vc + i0, 8);
      __builtin_memcpy(&q1, vc + i1, 8);
      __builtin_memcpy(&q2, vc + i2, 8);
      __builtin_memcpy(&q3, vc + i3, 8);
      a = fmaf(w0A, q0.x, a); a = fmaf(w0B, q0.y, a);
      a = fmaf(w1A, q1.x, a); a = fmaf(w1B, q1.y, a);
      a = fmaf(w2A, q2.x, a); a = fmaf(w2B, q2.y, a);
      a = fmaf(w3A, q3.x, a); a = fmaf(w3B, q3.y, a);
      acc_s[c * 256 + tid] = a;
    }
  }

  // ---- epilogue ----
  for (int c = 0; c < CG; ++c)
    out[((size_t)(g * CG + c)) * NN + n] = acc_s[c * 256 + tid];
}

// --------- per-channel mean / rstd over N (instance norm stats) -------------
__global__ __launch_bounds__(256)
void stats_kernel(const float* __restrict__ y, float* __restrict__ mean,
                  float* __restrict__ rstd) {
  const int c = blockIdx.x;
  const float* __restrict__ yc = y + (size_t)c * NN;
  float s = 0.f, ss = 0.f;
  for (int i = threadIdx.x; i < NN; i += 256) {
    const float v = yc[i];
    s += v;
    ss = fmaf(v, v, ss);
  }
  __shared__ float sh1[256], sh2[256];
  sh1[threadIdx.x] = s;
  sh2[threadIdx.x] = ss;
  __syncthreads();
  for (int o = 128; o > 0; o >>= 1) {
    if (threadIdx.x < o) {
      sh1[threadIdx.x] += sh1[threadIdx.x + o];
      sh2[threadIdx.x] += sh2[threadIdx.x + o];
    }
    __syncthreads();
  }
  if (threadIdx.x == 0) {
    const float mu = sh1[0] / (float)NN;
    const float var = sh2[0] / (float)NN - mu * mu;
    mean[c] = mu;
    rstd[c] = rsqrtf(var + 1e-5f);
  }
}

// --------- normalize + exact GELU (elementwise over [64][N]) ----------------
__global__ __launch_bounds__(256)
void normgelu_kernel(const float* __restrict__ y, const float* __restrict__ mean,
                     const float* __restrict__ rstd, float* __restrict__ out) {
  const int i = blockIdx.x * 256 + threadIdx.x;
  const int c = i >> 17;  // NN = 2^17
  out[i] = gelu_f((y[i] - mean[c]) * rstd[c]);
}

// --------- post conv1x1 + gated residual: out = c + sg * (Wpost r) ----------
__global__ __launch_bounds__(256)
void post_residual_kernel(const float* __restrict__ r, const float* __restrict__ wpost,
                          const float* __restrict__ cbuf, const float* __restrict__ gate,
                          float* __restrict__ out) {
  const int n = blockIdx.x * 256 + threadIdx.x;
  const float sg = 1.f / (1.f + expf(-gate[0]));
  float acc[64];
#pragma unroll
  for (int o = 0; o < 64; ++o) acc[o] = 0.f;
  for (int c = 0; c < 64; ++c) {
    const float rc = r[(size_t)c * NN + n];
#pragma unroll
    for (int o = 0; o < 64; ++o) acc[o] = fmaf(wpost[o * 64 + c], rc, acc[o]);
  }
#pragma unroll
  for (int o = 0; o < 64; ++o)
    out[(size_t)o * NN + n] = cbuf[(size_t)o * NN + n] + sg * acc[o];
}

// --------- 2x2x2 max pool, stride 2 -----------------------------------------
__global__ __launch_bounds__(256)
void maxpool_kernel(const float* __restrict__ x, float* __restrict__ y) {
  const int i = blockIdx.x * 256 + threadIdx.x;  // 64*16*32*32
  const int ow = i & 31;
  const int oh = (i >> 5) & 31;
  const int od = (i >> 10) & 15;
  const int c = i >> 14;
  const float* __restrict__ xc =
      x + (size_t)c * NN + ((size_t)(od * 2) * HHm + oh * 2) * WWm + ow * 2;
  float m = -INFINITY;
#pragma unroll
  for (int dz = 0; dz < 2; ++dz)
#pragma unroll
    for (int dy = 0; dy < 2; ++dy)
#pragma unroll
      for (int dx = 0; dx < 2; ++dx)
        m = fmaxf(m, xc[(dz * HHm + dy) * WWm + dx]);
  y[i] = m;
}

extern "C" void kernel_launch(void* const* d_in, const int* in_sizes, int n_in,
                              void* d_out, int out_size, void* d_ws, size_t ws_size,
                              hipStream_t stream) {
  const float* x       = (const float*)d_in[0];
  const float* d1_win  = (const float*)d_in[1];
  const float* d1_wdw  = (const float*)d_in[2];
  const float* d1_woff = (const float*)d_in[3];
  const float* d1_boff = (const float*)d_in[4];
  const float* d1_wmask= (const float*)d_in[5];
  const float* d1_bmask= (const float*)d_in[6];
  const float* d1_wout = (const float*)d_in[7];
  const float* d2_win  = (const float*)d_in[8];
  const float* d2_wdw  = (const float*)d_in[9];
  const float* d2_woff = (const float*)d_in[10];
  const float* d2_boff = (const float*)d_in[11];
  const float* d2_wmask= (const float*)d_in[12];
  const float* d2_bmask= (const float*)d_in[13];
  const float* d2_wout = (const float*)d_in[14];
  const float* pre_w   = (const float*)d_in[15];
  const float* d3_win  = (const float*)d_in[16];
  const float* d3_wdw  = (const float*)d_in[17];
  const float* d3_woff = (const float*)d_in[18];
  const float* d3_boff = (const float*)d_in[19];
  const float* d3_wmask= (const float*)d_in[20];
  const float* d3_bmask= (const float*)d_in[21];
  const float* d3_wout = (const float*)d_in[22];
  const float* post_w  = (const float*)d_in[23];
  const float* gate    = (const float*)d_in[24];

  float* out = (float*)d_out;

  // workspace layout: 5 x [64*NN] fp32 buffers + stats
  float* Wv = (float*)d_ws;          // value proj / pre-norm y (aliased)
  float* Wz = Wv + (size_t)64 * NN;  // dwconv+gelu branch
  float* Wa = Wz + (size_t)64 * NN;  // DCN sampling accumulator
  float* Wc = Wa + (size_t)64 * NN;  // residual trunk 'c'
  float* Wr = Wc + (size_t)64 * NN;  // refine branch 'r'
  float* Wm = Wr + (size_t)64 * NN;  // mean[64]
  float* Ws = Wm + 64;               // rstd[64]

  const dim3 blk(256);
  const int nb = NN / 256;  // 512

  // ---- stage d1: 32ch -> 64ch, G=4, Cg=8 ----
  conv1x1_kernel<32, 32><<<nb, blk, 0, stream>>>(x, d1_win, Wv);
  dw3_gelu_kernel<<<dim3(nb, 32), blk, 0, stream>>>(Wv, d1_wdw, Wz);
  dcn_fused_kernel<32, 4, 8><<<dim3(nb, 4), blk, 0, stream>>>(
      Wv, Wz, d1_woff, d1_boff, d1_wmask, d1_bmask, Wa, 1.f);
  conv1x1_kernel<32, 64><<<nb, blk, 0, stream>>>(Wa, d1_wout, Wv);
  stats_kernel<<<64, blk, 0, stream>>>(Wv, Wm, Ws);
  normgelu_kernel<<<64 * nb, blk, 0, stream>>>(Wv, Wm, Ws, Wc);

  // ---- stage d2: 64ch -> 64ch, G=4, Cg=16 ----
  conv1x1_kernel<64, 64><<<nb, blk, 0, stream>>>(Wc, d2_win, Wv);
  dw3_gelu_kernel<<<dim3(nb, 64), blk, 0, stream>>>(Wv, d2_wdw, Wz);
  dcn_fused_kernel<64, 4, 16><<<dim3(nb, 4), blk, 0, stream>>>(
      Wv, Wz, d2_woff, d2_boff, d2_wmask, d2_bmask, Wa, 1.f);
  conv1x1_kernel<64, 64><<<nb, blk, 0, stream>>>(Wa, d2_wout, Wv);
  stats_kernel<<<64, blk, 0, stream>>>(Wv, Wm, Ws);
  normgelu_kernel<<<64 * nb, blk, 0, stream>>>(Wv, Wm, Ws, Wc);

  // ---- pre conv ----
  conv1x1_kernel<64, 64><<<nb, blk, 0, stream>>>(Wc, pre_w, Wr);

  // ---- stage d3: 64ch -> 64ch, G=2, Cg=32, axis_scale=(0.5,1,1) ----
  conv1x1_kernel<64, 64><<<nb, blk, 0, stream>>>(Wr, d3_win, Wv);
  dw3_gelu_kernel<<<dim3(nb, 64), blk, 0, stream>>>(Wv, d3_wdw, Wz);
  dcn_fused_kernel<64, 2, 32><<<dim3(nb, 2), blk, 0, stream>>>(
      Wv, Wz, d3_woff, d3_boff, d3_wmask, d3_bmask, Wa, 0.5f);
  conv1x1_kernel<64, 64><<<nb, blk, 0, stream>>>(Wa, d3_wout, Wv);
  stats_kernel<<<64, blk, 0, stream>>>(Wv, Wm, Ws);
  normgelu_kernel<<<64 * nb, blk, 0, stream>>>(Wv, Wm, Ws, Wr);

  // ---- post conv + gated residual into conv_out ----
  post_residual_kernel<<<nb, blk, 0, stream>>>(Wr, post_w, Wc, gate, out);

  // ---- maxpool into second output ----
  maxpool_kernel<<<(64 * 16 * 32 * 32) / 256, blk, 0, stream>>>(
      out, out + (size_t)64 * NN);
}